// Round 1
// baseline (550.924 us; speedup 1.0000x reference)
//
#include <hip/hip_runtime.h>
#include <math.h>

#define N_NODES   100000
#define N_EDGES   1600000
#define D_FEAT    64
#define N_CH      64

// ---------------------------------------------------------------------------
// Kernel 1: seed output accumulator with skip_weight (broadcast over rows).
// out[i][c] = skip[c]; edge kernel then atomically accumulates into it.
// ---------------------------------------------------------------------------
__global__ __launch_bounds__(256) void init_out_kernel(
    float* __restrict__ out, const float* __restrict__ skip)
{
    int idx = blockIdx.x * 256 + threadIdx.x;
    if (idx < N_NODES * N_CH) {
        out[idx] = skip[idx & (N_CH - 1)];
    }
}

// ---------------------------------------------------------------------------
// Kernel 2: dense transform h = features @ kernel + bias  (f32, vector FMA).
// One wave per group of rows; lane = output channel. Kernel matrix (16 KB)
// staged in LDS; feature row loaded coalesced then broadcast via __shfl.
// ---------------------------------------------------------------------------
#define ROWS_PER_WAVE 8
#define ROWS_PER_BLOCK (4 * ROWS_PER_WAVE)   // 4 waves / 256-thread block

__global__ __launch_bounds__(256) void gemm_kernel(
    const float* __restrict__ feat,
    const float* __restrict__ W,
    const float* __restrict__ bias,
    float* __restrict__ h)
{
    __shared__ float Wlds[D_FEAT * N_CH];   // 16 KB

    int tid = threadIdx.x;
    // cooperative load of the 64x64 kernel matrix (coalesced float4)
    const float4* Wv = reinterpret_cast<const float4*>(W);
    float4* Wl = reinterpret_cast<float4*>(Wlds);
    for (int i = tid; i < (D_FEAT * N_CH) / 4; i += 256) {
        Wl[i] = Wv[i];
    }
    __syncthreads();

    int lane = tid & 63;
    int wave = tid >> 6;
    int row0 = (blockIdx.x * 4 + wave) * ROWS_PER_WAVE;
    float b = bias[lane];

    for (int r = 0; r < ROWS_PER_WAVE; ++r) {
        int row = row0 + r;
        if (row >= N_NODES) return;
        // coalesced 256B load of the feature row: lane k holds feat[row][k]
        float fv = feat[row * D_FEAT + lane];
        float acc = b;
        #pragma unroll
        for (int k = 0; k < D_FEAT; ++k) {
            float f = __shfl(fv, k, 64);                 // broadcast feat[row][k]
            acc = fmaf(f, Wlds[k * N_CH + lane], acc);   // lanes hit 32 banks 2-way: free
        }
        h[row * N_CH + lane] = acc;
    }
}

// ---------------------------------------------------------------------------
// Kernel 3: COO edge scatter.  One wave per edge, lane = channel.
// out[row[e]][c] += vals[e] * h[col[e]][c]   via coalesced f32 atomics.
// ---------------------------------------------------------------------------
__global__ __launch_bounds__(256) void edge_kernel(
    const float* __restrict__ vals,
    const int*   __restrict__ rows,
    const int*   __restrict__ cols,
    const float* __restrict__ h,
    float*       __restrict__ out)
{
    int e = blockIdx.x * 4 + (threadIdx.x >> 6);   // global wave id = edge id
    int lane = threadIdx.x & 63;
    if (e >= N_EDGES) return;

    int   row = rows[e];   // same-address broadcast across the wave
    int   col = cols[e];
    float v   = vals[e];

    float m = v * h[col * N_CH + lane];            // coalesced 256B gather
    atomicAdd(&out[row * N_CH + lane], m);         // coalesced 256B atomic span
}

// ---------------------------------------------------------------------------
// Kernel 4: in-place SeLU.  out = scale * (x>0 ? x : alpha*expm1(x))
// ---------------------------------------------------------------------------
__global__ __launch_bounds__(256) void selu_kernel(float* __restrict__ out)
{
    int idx = blockIdx.x * 256 + threadIdx.x;
    if (idx >= N_NODES * N_CH) return;
    const float scale = 1.0507009873554805f;
    const float alpha = 1.6732632423543772f;
    float x = out[idx];
    float neg = scale * alpha * expm1f(x);
    out[idx] = x > 0.0f ? scale * x : neg;
}

// ---------------------------------------------------------------------------
extern "C" void kernel_launch(void* const* d_in, const int* in_sizes, int n_in,
                              void* d_out, int out_size, void* d_ws, size_t ws_size,
                              hipStream_t stream)
{
    const float* features = (const float*)d_in[0];   // [100000, 64]
    const float* W        = (const float*)d_in[1];   // [64, 64]
    const float* bias     = (const float*)d_in[2];   // [64]
    const float* skip     = (const float*)d_in[3];   // [64]
    const float* adj_vals = (const float*)d_in[4];   // [1.6M]
    const int*   adj_rows = (const int*)d_in[5];     // [1.6M]
    const int*   adj_cols = (const int*)d_in[6];     // [1.6M]

    float* out = (float*)d_out;                       // [100000, 64]
    float* h   = (float*)d_ws;                        // scratch: 25.6 MB

    // 1) out <- skip_weight (accumulator seed)
    init_out_kernel<<<(N_NODES * N_CH + 255) / 256, 256, 0, stream>>>(out, skip);

    // 2) h <- features @ W + bias
    gemm_kernel<<<(N_NODES + ROWS_PER_BLOCK - 1) / ROWS_PER_BLOCK, 256, 0, stream>>>(
        features, W, bias, h);

    // 3) scatter-add edges into out
    edge_kernel<<<(N_EDGES + 3) / 4, 256, 0, stream>>>(
        adj_vals, adj_rows, adj_cols, h, out);

    // 4) out <- selu(out)
    selu_kernel<<<(N_NODES * N_CH + 255) / 256, 256, 0, stream>>>(out);
}

// Round 2
// 400.268 us; speedup vs baseline: 1.3764x; 1.3764x over previous
//
#include <hip/hip_runtime.h>
#include <math.h>

#define N_NODES   100000
#define N_EDGES   1600000
#define D_FEAT    64
#define N_CH      64

#define SELU_SCALE 1.0507009873554805f
#define SELU_ALPHA 1.6732632423543772f

// ------------------------- scan config -------------------------
#define SCAN_TPB   256
#define SCAN_ELEMS 1024                                   // 4 per thread
#define SCAN_NB    ((N_NODES + SCAN_ELEMS - 1) / SCAN_ELEMS)   // 98

// ===========================================================================
// GEMM: h = features @ W + bias.  Lane = channel; W column cached in 64 VGPRs;
// feature row read via wave-uniform scalar loads (readfirstlane'd row id).
// ===========================================================================
#define G_ROWS_PER_WAVE 16
#define G_ROWS_PER_BLOCK (4 * G_ROWS_PER_WAVE)   // 64

__global__ __launch_bounds__(256) void gemm_kernel(
    const float* __restrict__ feat,
    const float* __restrict__ W,
    const float* __restrict__ bias,
    float* __restrict__ h)
{
    int lane = threadIdx.x & 63;
    int wave = threadIdx.x >> 6;

    // W[k][lane] for k=0..63 — coalesced 256B loads, L1/L2-hot after first wave
    float Wc[D_FEAT];
    #pragma unroll
    for (int k = 0; k < D_FEAT; ++k) Wc[k] = W[k * N_CH + lane];
    float b = bias[lane];

    int row0 = (blockIdx.x * 4 + wave) * G_ROWS_PER_WAVE;
    for (int r = 0; r < G_ROWS_PER_WAVE; ++r) {
        int row = row0 + r;
        if (row >= N_NODES) return;
        // wave-uniform row -> scalar (SMEM) loads of the feature row
        int row_u = __builtin_amdgcn_readfirstlane(row);
        const float* frow = feat + (size_t)row_u * D_FEAT;
        float a0 = b, a1 = 0.f, a2 = 0.f, a3 = 0.f;
        #pragma unroll
        for (int k = 0; k < D_FEAT; k += 4) {
            a0 = fmaf(frow[k + 0], Wc[k + 0], a0);
            a1 = fmaf(frow[k + 1], Wc[k + 1], a1);
            a2 = fmaf(frow[k + 2], Wc[k + 2], a2);
            a3 = fmaf(frow[k + 3], Wc[k + 3], a3);
        }
        h[row * N_CH + lane] = (a0 + a1) + (a2 + a3);
    }
}

// ===========================================================================
// CSR build
// ===========================================================================
__global__ __launch_bounds__(256) void zero_deg_kernel(int* __restrict__ deg)
{
    int i = blockIdx.x * 256 + threadIdx.x;
    if (i < N_NODES) deg[i] = 0;
}

__global__ __launch_bounds__(256) void degree_kernel(
    const int* __restrict__ rows, int* __restrict__ deg)
{
    int e = blockIdx.x * 256 + threadIdx.x;
    if (e < N_EDGES) atomicAdd(&deg[rows[e]], 1);
}

// exclusive scan, pass 1: per-block scan of 1024 elems (in deg -> row_start),
// block total to partials[b]
__global__ __launch_bounds__(SCAN_TPB) void scan1_kernel(
    const int* __restrict__ deg, int* __restrict__ row_start,
    int* __restrict__ partials)
{
    __shared__ int lds[SCAN_TPB];
    int t = threadIdx.x;
    int base = blockIdx.x * SCAN_ELEMS + t * 4;
    int v0 = (base + 0 < N_NODES) ? deg[base + 0] : 0;
    int v1 = (base + 1 < N_NODES) ? deg[base + 1] : 0;
    int v2 = (base + 2 < N_NODES) ? deg[base + 2] : 0;
    int v3 = (base + 3 < N_NODES) ? deg[base + 3] : 0;
    int s1 = v0, s2 = v0 + v1, s3 = v0 + v1 + v2, tot = v0 + v1 + v2 + v3;
    lds[t] = tot;
    __syncthreads();
    for (int off = 1; off < SCAN_TPB; off <<= 1) {
        int y = (t >= off) ? lds[t - off] : 0;
        __syncthreads();
        lds[t] += y;
        __syncthreads();
    }
    int texcl = (t > 0) ? lds[t - 1] : 0;
    if (t == SCAN_TPB - 1) partials[blockIdx.x] = lds[SCAN_TPB - 1];
    if (base + 0 < N_NODES) row_start[base + 0] = texcl;
    if (base + 1 < N_NODES) row_start[base + 1] = texcl + s1;
    if (base + 2 < N_NODES) row_start[base + 2] = texcl + s2;
    if (base + 3 < N_NODES) row_start[base + 3] = texcl + s3;
}

// pass 2: exclusive scan of the block partials (single block)
__global__ __launch_bounds__(128) void scan2_kernel(int* __restrict__ partials)
{
    __shared__ int lds[128];
    int t = threadIdx.x;
    lds[t] = (t < SCAN_NB) ? partials[t] : 0;
    __syncthreads();
    for (int off = 1; off < 128; off <<= 1) {
        int y = (t >= off) ? lds[t - off] : 0;
        __syncthreads();
        lds[t] += y;
        __syncthreads();
    }
    if (t < SCAN_NB) partials[t] = (t > 0) ? lds[t - 1] : 0;
}

// pass 3: add block offset, produce final row_start + cursor copy + sentinel
__global__ __launch_bounds__(SCAN_TPB) void scan3_kernel(
    int* __restrict__ row_start, int* __restrict__ cursor,
    const int* __restrict__ partials)
{
    int t = threadIdx.x;
    int add = partials[blockIdx.x];
    int base = blockIdx.x * SCAN_ELEMS + t * 4;
    #pragma unroll
    for (int j = 0; j < 4; ++j) {
        int idx = base + j;
        if (idx < N_NODES) {
            int v = row_start[idx] + add;
            row_start[idx] = v;
            cursor[idx] = v;
        }
    }
    if (blockIdx.x == 0 && t == 0) row_start[N_NODES] = N_EDGES;
}

// scatter edges into CSR order: pack = (col, val) as 8B
__global__ __launch_bounds__(256) void scatter_kernel(
    const int* __restrict__ rows, const int* __restrict__ cols,
    const float* __restrict__ vals,
    int* __restrict__ cursor, uint2* __restrict__ pack)
{
    int e = blockIdx.x * 256 + threadIdx.x;
    if (e < N_EDGES) {
        int r = rows[e];
        int pos = atomicAdd(&cursor[r], 1);
        pack[pos] = make_uint2((unsigned)cols[e], __float_as_uint(vals[e]));
    }
}

// ===========================================================================
// Aggregate: one wave per row, lane = channel.  Edges of the row loaded as a
// 64-wide vector, broadcast via shfl; 4 independent fma/gather chains.
// Fused epilogue: + skip_weight, SeLU.
// ===========================================================================
__global__ __launch_bounds__(256) void aggregate_kernel(
    const int*   __restrict__ row_start,
    const uint2* __restrict__ pack,
    const float* __restrict__ h,
    const float* __restrict__ skip,
    float*       __restrict__ out)
{
    int row  = blockIdx.x * 4 + (threadIdx.x >> 6);
    int lane = threadIdx.x & 63;
    if (row >= N_NODES) return;

    int s = row_start[row];
    int e = row_start[row + 1];

    float a0 = 0.f, a1 = 0.f, a2 = 0.f, a3 = 0.f;
    for (int j = s; j < e; j += 64) {
        int cnt = e - j;
        if (cnt > 64) cnt = 64;
        uint2 p = make_uint2(0u, 0u);          // v=0 padding -> fma adds 0
        if (lane < cnt) p = pack[j + lane];    // coalesced 512B
        int pc = (cnt + 3) & ~3;
        for (int k = 0; k < pc; k += 4) {
            int   c0 = __shfl((int)p.x, k + 0, 64);
            float v0 = __shfl(__uint_as_float(p.y), k + 0, 64);
            int   c1 = __shfl((int)p.x, k + 1, 64);
            float v1 = __shfl(__uint_as_float(p.y), k + 1, 64);
            int   c2 = __shfl((int)p.x, k + 2, 64);
            float v2 = __shfl(__uint_as_float(p.y), k + 2, 64);
            int   c3 = __shfl((int)p.x, k + 3, 64);
            float v3 = __shfl(__uint_as_float(p.y), k + 3, 64);
            a0 = fmaf(v0, h[c0 * N_CH + lane], a0);
            a1 = fmaf(v1, h[c1 * N_CH + lane], a1);
            a2 = fmaf(v2, h[c2 * N_CH + lane], a2);
            a3 = fmaf(v3, h[c3 * N_CH + lane], a3);
        }
    }
    float x = (a0 + a1) + (a2 + a3) + skip[lane];
    float neg = SELU_SCALE * SELU_ALPHA * expm1f(x);
    out[row * N_CH + lane] = x > 0.f ? SELU_SCALE * x : neg;
}

// ===========================================================================
// Fallback path (ws too small): proven Round-0 atomic version
// ===========================================================================
__global__ __launch_bounds__(256) void init_out_kernel(
    float* __restrict__ out, const float* __restrict__ skip)
{
    int idx = blockIdx.x * 256 + threadIdx.x;
    if (idx < N_NODES * N_CH) out[idx] = skip[idx & (N_CH - 1)];
}

__global__ __launch_bounds__(256) void edge_kernel(
    const float* __restrict__ vals, const int* __restrict__ rows,
    const int* __restrict__ cols, const float* __restrict__ h,
    float* __restrict__ out)
{
    int e = blockIdx.x * 4 + (threadIdx.x >> 6);
    int lane = threadIdx.x & 63;
    if (e >= N_EDGES) return;
    int row = rows[e];
    int col = cols[e];
    float v = vals[e];
    atomicAdd(&out[row * N_CH + lane], v * h[col * N_CH + lane]);
}

__global__ __launch_bounds__(256) void selu_kernel(float* __restrict__ out)
{
    int idx = blockIdx.x * 256 + threadIdx.x;
    if (idx >= N_NODES * N_CH) return;
    float x = out[idx];
    float neg = SELU_SCALE * SELU_ALPHA * expm1f(x);
    out[idx] = x > 0.f ? SELU_SCALE * x : neg;
}

// ===========================================================================
static inline size_t align256(size_t x) { return (x + 255) & ~(size_t)255; }

extern "C" void kernel_launch(void* const* d_in, const int* in_sizes, int n_in,
                              void* d_out, int out_size, void* d_ws, size_t ws_size,
                              hipStream_t stream)
{
    const float* features = (const float*)d_in[0];
    const float* W        = (const float*)d_in[1];
    const float* bias     = (const float*)d_in[2];
    const float* skip     = (const float*)d_in[3];
    const float* adj_vals = (const float*)d_in[4];
    const int*   adj_rows = (const int*)d_in[5];
    const int*   adj_cols = (const int*)d_in[6];
    float* out = (float*)d_out;

    // ---- workspace carve-up ----
    char* ws = (char*)d_ws;
    size_t off = 0;
    float* h = (float*)(ws + off);         off = align256(off + (size_t)N_NODES * N_CH * 4);
    int* row_start = (int*)(ws + off);     off = align256(off + (size_t)(N_NODES + 1) * 4);
    int* cursor    = (int*)(ws + off);     off = align256(off + (size_t)N_NODES * 4);
    int* deg       = (int*)(ws + off);     off = align256(off + (size_t)N_NODES * 4);
    int* partials  = (int*)(ws + off);     off = align256(off + 128 * 4);
    uint2* pack    = (uint2*)(ws + off);   off = align256(off + (size_t)N_EDGES * 8);
    size_t need = off;

    // h = features @ W + bias  (common to both paths)
    gemm_kernel<<<(N_NODES + G_ROWS_PER_BLOCK - 1) / G_ROWS_PER_BLOCK, 256, 0, stream>>>(
        features, W, bias, h);

    if (ws_size >= need) {
        // ---- CSR build ----
        zero_deg_kernel<<<(N_NODES + 255) / 256, 256, 0, stream>>>(deg);
        degree_kernel<<<(N_EDGES + 255) / 256, 256, 0, stream>>>(adj_rows, deg);
        scan1_kernel<<<SCAN_NB, SCAN_TPB, 0, stream>>>(deg, row_start, partials);
        scan2_kernel<<<1, 128, 0, stream>>>(partials);
        scan3_kernel<<<SCAN_NB, SCAN_TPB, 0, stream>>>(row_start, cursor, partials);
        scatter_kernel<<<(N_EDGES + 255) / 256, 256, 0, stream>>>(
            adj_rows, adj_cols, adj_vals, cursor, pack);
        // ---- gather-aggregate + skip + SeLU ----
        aggregate_kernel<<<(N_NODES + 3) / 4, 256, 0, stream>>>(
            row_start, pack, h, skip, out);
    } else {
        // ---- fallback: atomic scatter ----
        init_out_kernel<<<(N_NODES * N_CH + 255) / 256, 256, 0, stream>>>(out, skip);
        edge_kernel<<<(N_EDGES + 3) / 4, 256, 0, stream>>>(
            adj_vals, adj_rows, adj_cols, h, out);
        selu_kernel<<<(N_NODES * N_CH + 255) / 256, 256, 0, stream>>>(out);
    }
}

// Round 7
// 348.364 us; speedup vs baseline: 1.5815x; 1.1490x over previous
//
#include <hip/hip_runtime.h>
#include <math.h>

#define N_NODES   100000
#define N_EDGES   1600000
#define D_FEAT    64
#define N_CH      64

#define SELU_SCALE 1.0507009873554805f
#define SELU_ALPHA 1.6732632423543772f

// ------------------------- scan config -------------------------
#define SCAN_TPB   256
#define SCAN_ELEMS 1024                                   // 4 per thread
#define SCAN_NB    ((N_NODES + SCAN_ELEMS - 1) / SCAN_ELEMS)   // 98

// ------------------------- gemm config -------------------------
#define G_ROWS_PER_WAVE 16
#define G_ROWS_PER_BLOCK (4 * G_ROWS_PER_WAVE)   // 64
#define NB_GEMM  ((N_NODES + G_ROWS_PER_BLOCK - 1) / G_ROWS_PER_BLOCK)  // 1563
#define NB_SCAT4 ((N_EDGES / 4 + 255) / 256)     // 1563 (4 edges per thread)

// ===========================================================================
// GEMM body: h = features @ W + bias.  Lane = channel; W column in 64 VGPRs;
// feature row via wave-uniform scalar loads.  Called from the fused kernel.
// ===========================================================================
__device__ __forceinline__ void gemm_body(
    int gb,
    const float* __restrict__ feat,
    const float* __restrict__ W,
    const float* __restrict__ bias,
    float* __restrict__ h)
{
    int lane = threadIdx.x & 63;
    int wave = threadIdx.x >> 6;

    float Wc[D_FEAT];
    #pragma unroll
    for (int k = 0; k < D_FEAT; ++k) Wc[k] = W[k * N_CH + lane];
    float b = bias[lane];

    int row0 = (gb * 4 + wave) * G_ROWS_PER_WAVE;
    for (int r = 0; r < G_ROWS_PER_WAVE; ++r) {
        int row = row0 + r;
        if (row >= N_NODES) return;
        int row_u = __builtin_amdgcn_readfirstlane(row);
        const float* frow = feat + (size_t)row_u * D_FEAT;
        float a0 = b, a1 = 0.f, a2 = 0.f, a3 = 0.f;
        #pragma unroll
        for (int k = 0; k < D_FEAT; k += 4) {
            a0 = fmaf(frow[k + 0], Wc[k + 0], a0);
            a1 = fmaf(frow[k + 1], Wc[k + 1], a1);
            a2 = fmaf(frow[k + 2], Wc[k + 2], a2);
            a3 = fmaf(frow[k + 3], Wc[k + 3], a3);
        }
        h[row * N_CH + lane] = (a0 + a1) + (a2 + a3);
    }
}

// ===========================================================================
// CSR build, pass 1: degree histogram + per-edge rank (the atomic's return
// value IS the rank within the row — saves a whole atomic pass later).
// ===========================================================================
__global__ __launch_bounds__(256) void zero_deg_kernel(int* __restrict__ deg)
{
    int i = blockIdx.x * 256 + threadIdx.x;
    if (i < N_NODES) deg[i] = 0;
}

__global__ __launch_bounds__(256) void degree_rank_kernel(
    const int* __restrict__ rows, int* __restrict__ deg, int* __restrict__ rank)
{
    int i = blockIdx.x * 256 + threadIdx.x;
    if (i < N_EDGES / 4) {
        const int4 r = reinterpret_cast<const int4*>(rows)[i];
        int4 k;
        k.x = atomicAdd(&deg[r.x], 1);
        k.y = atomicAdd(&deg[r.y], 1);
        k.z = atomicAdd(&deg[r.z], 1);
        k.w = atomicAdd(&deg[r.w], 1);
        reinterpret_cast<int4*>(rank)[i] = k;
    }
}

// ===========================================================================
// Exclusive scan of deg -> row_start (3 kernels)
// ===========================================================================
__global__ __launch_bounds__(SCAN_TPB) void scan1_kernel(
    const int* __restrict__ deg, int* __restrict__ row_start,
    int* __restrict__ partials)
{
    __shared__ int lds[SCAN_TPB];
    int t = threadIdx.x;
    int base = blockIdx.x * SCAN_ELEMS + t * 4;
    int v0 = (base + 0 < N_NODES) ? deg[base + 0] : 0;
    int v1 = (base + 1 < N_NODES) ? deg[base + 1] : 0;
    int v2 = (base + 2 < N_NODES) ? deg[base + 2] : 0;
    int v3 = (base + 3 < N_NODES) ? deg[base + 3] : 0;
    int s1 = v0, s2 = v0 + v1, s3 = v0 + v1 + v2, tot = v0 + v1 + v2 + v3;
    lds[t] = tot;
    __syncthreads();
    for (int off = 1; off < SCAN_TPB; off <<= 1) {
        int y = (t >= off) ? lds[t - off] : 0;
        __syncthreads();
        lds[t] += y;
        __syncthreads();
    }
    int texcl = (t > 0) ? lds[t - 1] : 0;
    if (t == SCAN_TPB - 1) partials[blockIdx.x] = lds[SCAN_TPB - 1];
    if (base + 0 < N_NODES) row_start[base + 0] = texcl;
    if (base + 1 < N_NODES) row_start[base + 1] = texcl + s1;
    if (base + 2 < N_NODES) row_start[base + 2] = texcl + s2;
    if (base + 3 < N_NODES) row_start[base + 3] = texcl + s3;
}

__global__ __launch_bounds__(128) void scan2_kernel(int* __restrict__ partials)
{
    __shared__ int lds[128];
    int t = threadIdx.x;
    lds[t] = (t < SCAN_NB) ? partials[t] : 0;
    __syncthreads();
    for (int off = 1; off < 128; off <<= 1) {
        int y = (t >= off) ? lds[t - off] : 0;
        __syncthreads();
        lds[t] += y;
        __syncthreads();
    }
    if (t < SCAN_NB) partials[t] = (t > 0) ? lds[t - 1] : 0;
}

__global__ __launch_bounds__(SCAN_TPB) void scan3_kernel(
    int* __restrict__ row_start, const int* __restrict__ partials)
{
    int t = threadIdx.x;
    int add = partials[blockIdx.x];
    int base = blockIdx.x * SCAN_ELEMS + t * 4;
    #pragma unroll
    for (int j = 0; j < 4; ++j) {
        int idx = base + j;
        if (idx < N_NODES) row_start[idx] += add;
    }
    if (blockIdx.x == 0 && t == 0) row_start[N_NODES] = N_EDGES;
}

// ===========================================================================
// Fused: non-atomic CSR scatter (perm[row_start+rank]=e)  ||  GEMM.
// Role-split by blockIdx: scatter is latency/writethrough-bound, GEMM is
// compute/BW-bound -> they overlap on the machine.
// ===========================================================================
__global__ __launch_bounds__(256) void scatter_gemm_kernel(
    const int* __restrict__ rows, const int* __restrict__ rank,
    const int* __restrict__ row_start, int* __restrict__ perm,
    const float* __restrict__ feat, const float* __restrict__ W,
    const float* __restrict__ bias, float* __restrict__ h)
{
    if (blockIdx.x < NB_SCAT4) {
        int i = blockIdx.x * 256 + threadIdx.x;
        if (i < N_EDGES / 4) {
            const int4 r  = reinterpret_cast<const int4*>(rows)[i];
            const int4 rk = reinterpret_cast<const int4*>(rank)[i];
            int e0 = i * 4;
            perm[row_start[r.x] + rk.x] = e0 + 0;
            perm[row_start[r.y] + rk.y] = e0 + 1;
            perm[row_start[r.z] + rk.z] = e0 + 2;
            perm[row_start[r.w] + rk.w] = e0 + 3;
        }
    } else {
        gemm_body(blockIdx.x - NB_SCAT4, feat, W, bias, h);
    }
}

// ===========================================================================
// Aggregate: one wave per row, lane = channel.  Reads perm (eid) coalesced,
// gathers cols/vals (L3-hot), broadcasts via shfl, 4 fma/gather chains.
// Fused epilogue: + skip_weight, SeLU.
// ===========================================================================
__global__ __launch_bounds__(256) void aggregate_kernel(
    const int*   __restrict__ row_start,
    const int*   __restrict__ perm,
    const int*   __restrict__ cols,
    const float* __restrict__ vals,
    const float* __restrict__ h,
    const float* __restrict__ skip,
    float*       __restrict__ out)
{
    int row  = blockIdx.x * 4 + (threadIdx.x >> 6);
    int lane = threadIdx.x & 63;
    if (row >= N_NODES) return;

    int s = row_start[row];
    int e = row_start[row + 1];

    float a0 = 0.f, a1 = 0.f, a2 = 0.f, a3 = 0.f;
    for (int j = s; j < e; j += 64) {
        int cnt = e - j;
        if (cnt > 64) cnt = 64;
        int   c = 0;
        float v = 0.f;                         // v=0 padding -> fma adds 0
        if (lane < cnt) {
            int eid = perm[j + lane];          // coalesced 256B
            c = cols[eid];                     // scattered 4B (L3-hot)
            v = vals[eid];                     // scattered 4B (L3-hot)
        }
        int pc = (cnt + 3) & ~3;
        for (int k = 0; k < pc; k += 4) {
            int   c0 = __shfl(c, k + 0, 64);
            float v0 = __shfl(v, k + 0, 64);
            int   c1 = __shfl(c, k + 1, 64);
            float v1 = __shfl(v, k + 1, 64);
            int   c2 = __shfl(c, k + 2, 64);
            float v2 = __shfl(v, k + 2, 64);
            int   c3 = __shfl(c, k + 3, 64);
            float v3 = __shfl(v, k + 3, 64);
            a0 = fmaf(v0, h[c0 * N_CH + lane], a0);
            a1 = fmaf(v1, h[c1 * N_CH + lane], a1);
            a2 = fmaf(v2, h[c2 * N_CH + lane], a2);
            a3 = fmaf(v3, h[c3 * N_CH + lane], a3);
        }
    }
    float x = (a0 + a1) + (a2 + a3) + skip[lane];
    float neg = SELU_SCALE * SELU_ALPHA * expm1f(x);
    out[row * N_CH + lane] = x > 0.f ? SELU_SCALE * x : neg;
}

// ===========================================================================
// Fallback path (ws too small): Round-0 atomic version
// ===========================================================================
__global__ __launch_bounds__(256) void gemm_only_kernel(
    const float* __restrict__ feat, const float* __restrict__ W,
    const float* __restrict__ bias, float* __restrict__ h)
{
    gemm_body(blockIdx.x, feat, W, bias, h);
}

__global__ __launch_bounds__(256) void init_out_kernel(
    float* __restrict__ out, const float* __restrict__ skip)
{
    int idx = blockIdx.x * 256 + threadIdx.x;
    if (idx < N_NODES * N_CH) out[idx] = skip[idx & (N_CH - 1)];
}

__global__ __launch_bounds__(256) void edge_kernel(
    const float* __restrict__ vals, const int* __restrict__ rows,
    const int* __restrict__ cols, const float* __restrict__ h,
    float* __restrict__ out)
{
    int e = blockIdx.x * 4 + (threadIdx.x >> 6);
    int lane = threadIdx.x & 63;
    if (e >= N_EDGES) return;
    int row = rows[e];
    int col = cols[e];
    float v = vals[e];
    atomicAdd(&out[row * N_CH + lane], v * h[col * N_CH + lane]);
}

__global__ __launch_bounds__(256) void selu_kernel(float* __restrict__ out)
{
    int idx = blockIdx.x * 256 + threadIdx.x;
    if (idx >= N_NODES * N_CH) return;
    float x = out[idx];
    float neg = SELU_SCALE * SELU_ALPHA * expm1f(x);
    out[idx] = x > 0.f ? SELU_SCALE * x : neg;
}

// ===========================================================================
static inline size_t align256(size_t x) { return (x + 255) & ~(size_t)255; }

extern "C" void kernel_launch(void* const* d_in, const int* in_sizes, int n_in,
                              void* d_out, int out_size, void* d_ws, size_t ws_size,
                              hipStream_t stream)
{
    const float* features = (const float*)d_in[0];
    const float* W        = (const float*)d_in[1];
    const float* bias     = (const float*)d_in[2];
    const float* skip     = (const float*)d_in[3];
    const float* adj_vals = (const float*)d_in[4];
    const int*   adj_rows = (const int*)d_in[5];
    const int*   adj_cols = (const int*)d_in[6];
    float* out = (float*)d_out;

    // ---- workspace carve-up ----
    char* ws = (char*)d_ws;
    size_t off = 0;
    float* h       = (float*)(ws + off);  off = align256(off + (size_t)N_NODES * N_CH * 4);
    int* row_start = (int*)(ws + off);    off = align256(off + (size_t)(N_NODES + 1) * 4);
    int* deg       = (int*)(ws + off);    off = align256(off + (size_t)N_NODES * 4);
    int* rank      = (int*)(ws + off);    off = align256(off + (size_t)N_EDGES * 4);
    int* perm      = (int*)(ws + off);    off = align256(off + (size_t)N_EDGES * 4);
    int* partials  = (int*)(ws + off);    off = align256(off + 128 * 4);
    size_t need = off;

    if (ws_size >= need) {
        // deg <- 0; rank[e] <- rank of e within its row (atomic return)
        zero_deg_kernel<<<(N_NODES + 255) / 256, 256, 0, stream>>>(deg);
        degree_rank_kernel<<<NB_SCAT4, 256, 0, stream>>>(adj_rows, deg, rank);
        // row_start <- exclusive_scan(deg)
        scan1_kernel<<<SCAN_NB, SCAN_TPB, 0, stream>>>(deg, row_start, partials);
        scan2_kernel<<<1, 128, 0, stream>>>(partials);
        scan3_kernel<<<SCAN_NB, SCAN_TPB, 0, stream>>>(row_start, partials);
        // perm scatter (non-atomic)  ||  h = feat @ W + bias
        scatter_gemm_kernel<<<NB_SCAT4 + NB_GEMM, 256, 0, stream>>>(
            adj_rows, rank, row_start, perm, features, W, bias, h);
        // gather-aggregate + skip + SeLU
        aggregate_kernel<<<(N_NODES + 3) / 4, 256, 0, stream>>>(
            row_start, perm, adj_cols, adj_vals, h, skip, out);
    } else {
        // ---- fallback: atomic scatter ----
        gemm_only_kernel<<<NB_GEMM, 256, 0, stream>>>(features, W, bias, h);
        init_out_kernel<<<(N_NODES * N_CH + 255) / 256, 256, 0, stream>>>(out, skip);
        edge_kernel<<<(N_EDGES + 3) / 4, 256, 0, stream>>>(
            adj_vals, adj_rows, adj_cols, h, out);
        selu_kernel<<<(N_NODES * N_CH + 255) / 256, 256, 0, stream>>>(out);
    }
}

// Round 9
// 312.031 us; speedup vs baseline: 1.7656x; 1.1164x over previous
//
#include <hip/hip_runtime.h>
#include <math.h>

#define N_NODES   100000
#define N_EDGES   1600000
#define D_FEAT    64
#define N_CH      64

#define SELU_SCALE 1.0507009873554805f
#define SELU_ALPHA 1.6732632423543772f

// ------------------------- scan config -------------------------
#define SCAN_TPB   256
#define SCAN_ELEMS 1024                                   // 4 per thread
#define SCAN_NB    ((N_NODES + SCAN_ELEMS - 1) / SCAN_ELEMS)   // 98

// ------------------------- gemm config -------------------------
#define G_ROWS_PER_WAVE 16
#define G_ROWS_PER_BLOCK (4 * G_ROWS_PER_WAVE)   // 64
#define NB_GEMM  ((N_NODES + G_ROWS_PER_BLOCK - 1) / G_ROWS_PER_BLOCK)  // 1563
#define NB_SCAT4 ((N_EDGES / 4 + 255) / 256)     // 1563 (4 edges per thread)

// ===========================================================================
// GEMM body: h = features @ W + bias.  Lane = channel; W column in 64 VGPRs;
// feature row via wave-uniform scalar loads.
// ===========================================================================
__device__ __forceinline__ void gemm_body(
    int gb,
    const float* __restrict__ feat,
    const float* __restrict__ W,
    const float* __restrict__ bias,
    float* __restrict__ h)
{
    int lane = threadIdx.x & 63;
    int wave = threadIdx.x >> 6;

    float Wc[D_FEAT];
    #pragma unroll
    for (int k = 0; k < D_FEAT; ++k) Wc[k] = W[k * N_CH + lane];
    float b = bias[lane];

    int row0 = (gb * 4 + wave) * G_ROWS_PER_WAVE;
    for (int r = 0; r < G_ROWS_PER_WAVE; ++r) {
        int row = row0 + r;
        if (row >= N_NODES) return;
        int row_u = __builtin_amdgcn_readfirstlane(row);
        const float* frow = feat + (size_t)row_u * D_FEAT;
        float a0 = b, a1 = 0.f, a2 = 0.f, a3 = 0.f;
        #pragma unroll
        for (int k = 0; k < D_FEAT; k += 4) {
            a0 = fmaf(frow[k + 0], Wc[k + 0], a0);
            a1 = fmaf(frow[k + 1], Wc[k + 1], a1);
            a2 = fmaf(frow[k + 2], Wc[k + 2], a2);
            a3 = fmaf(frow[k + 3], Wc[k + 3], a3);
        }
        h[row * N_CH + lane] = (a0 + a1) + (a2 + a3);
    }
}

// ===========================================================================
// CSR build, pass 1: degree histogram + per-edge rank (atomic return value).
// ===========================================================================
__global__ __launch_bounds__(256) void zero_deg_kernel(int* __restrict__ deg)
{
    int i = blockIdx.x * 256 + threadIdx.x;
    if (i < N_NODES) deg[i] = 0;
}

__global__ __launch_bounds__(256) void degree_rank_kernel(
    const int* __restrict__ rows, int* __restrict__ deg, int* __restrict__ rank)
{
    int i = blockIdx.x * 256 + threadIdx.x;
    if (i < N_EDGES / 4) {
        const int4 r = reinterpret_cast<const int4*>(rows)[i];
        int4 k;
        k.x = atomicAdd(&deg[r.x], 1);
        k.y = atomicAdd(&deg[r.y], 1);
        k.z = atomicAdd(&deg[r.z], 1);
        k.w = atomicAdd(&deg[r.w], 1);
        reinterpret_cast<int4*>(rank)[i] = k;
    }
}

// ===========================================================================
// Exclusive scan of deg -> row_start (3 kernels)
// ===========================================================================
__global__ __launch_bounds__(SCAN_TPB) void scan1_kernel(
    const int* __restrict__ deg, int* __restrict__ row_start,
    int* __restrict__ partials)
{
    __shared__ int lds[SCAN_TPB];
    int t = threadIdx.x;
    int base = blockIdx.x * SCAN_ELEMS + t * 4;
    int v0 = (base + 0 < N_NODES) ? deg[base + 0] : 0;
    int v1 = (base + 1 < N_NODES) ? deg[base + 1] : 0;
    int v2 = (base + 2 < N_NODES) ? deg[base + 2] : 0;
    int v3 = (base + 3 < N_NODES) ? deg[base + 3] : 0;
    int s1 = v0, s2 = v0 + v1, s3 = v0 + v1 + v2, tot = v0 + v1 + v2 + v3;
    lds[t] = tot;
    __syncthreads();
    for (int off = 1; off < SCAN_TPB; off <<= 1) {
        int y = (t >= off) ? lds[t - off] : 0;
        __syncthreads();
        lds[t] += y;
        __syncthreads();
    }
    int texcl = (t > 0) ? lds[t - 1] : 0;
    if (t == SCAN_TPB - 1) partials[blockIdx.x] = lds[SCAN_TPB - 1];
    if (base + 0 < N_NODES) row_start[base + 0] = texcl;
    if (base + 1 < N_NODES) row_start[base + 1] = texcl + s1;
    if (base + 2 < N_NODES) row_start[base + 2] = texcl + s2;
    if (base + 3 < N_NODES) row_start[base + 3] = texcl + s3;
}

__global__ __launch_bounds__(128) void scan2_kernel(int* __restrict__ partials)
{
    __shared__ int lds[128];
    int t = threadIdx.x;
    lds[t] = (t < SCAN_NB) ? partials[t] : 0;
    __syncthreads();
    for (int off = 1; off < 128; off <<= 1) {
        int y = (t >= off) ? lds[t - off] : 0;
        __syncthreads();
        lds[t] += y;
        __syncthreads();
    }
    if (t < SCAN_NB) partials[t] = (t > 0) ? lds[t - 1] : 0;
}

__global__ __launch_bounds__(SCAN_TPB) void scan3_kernel(
    int* __restrict__ row_start, const int* __restrict__ partials)
{
    int t = threadIdx.x;
    int add = partials[blockIdx.x];
    int base = blockIdx.x * SCAN_ELEMS + t * 4;
    #pragma unroll
    for (int j = 0; j < 4; ++j) {
        int idx = base + j;
        if (idx < N_NODES) row_start[idx] += add;
    }
    if (blockIdx.x == 0 && t == 0) row_start[N_NODES] = N_EDGES;
}

// ===========================================================================
// Fused: non-atomic CSR scatter of PACKED (col,val) 8B records || GEMM.
// NT stores via 64-bit integer alias (low 32 = col, high 32 = val bits —
// byte-identical to uint2{x=col,y=val} on little-endian).
// ===========================================================================
__global__ __launch_bounds__(256) void scatter_pack_gemm_kernel(
    const int* __restrict__ rows, const int* __restrict__ rank,
    const int* __restrict__ cols, const float* __restrict__ vals,
    const int* __restrict__ row_start, unsigned long long* __restrict__ pack64,
    const float* __restrict__ feat, const float* __restrict__ W,
    const float* __restrict__ bias, float* __restrict__ h)
{
    if (blockIdx.x < NB_SCAT4) {
        int i = blockIdx.x * 256 + threadIdx.x;
        if (i < N_EDGES / 4) {
            const int4   r  = reinterpret_cast<const int4*>(rows)[i];
            const int4   rk = reinterpret_cast<const int4*>(rank)[i];
            const int4   c  = reinterpret_cast<const int4*>(cols)[i];
            const float4 v  = reinterpret_cast<const float4*>(vals)[i];
            unsigned long long p0 =
                ((unsigned long long)__float_as_uint(v.x) << 32) | (unsigned)c.x;
            unsigned long long p1 =
                ((unsigned long long)__float_as_uint(v.y) << 32) | (unsigned)c.y;
            unsigned long long p2 =
                ((unsigned long long)__float_as_uint(v.z) << 32) | (unsigned)c.z;
            unsigned long long p3 =
                ((unsigned long long)__float_as_uint(v.w) << 32) | (unsigned)c.w;
            __builtin_nontemporal_store(p0, &pack64[row_start[r.x] + rk.x]);
            __builtin_nontemporal_store(p1, &pack64[row_start[r.y] + rk.y]);
            __builtin_nontemporal_store(p2, &pack64[row_start[r.z] + rk.z]);
            __builtin_nontemporal_store(p3, &pack64[row_start[r.w] + rk.w]);
        }
    } else {
        gemm_body(blockIdx.x - NB_SCAT4, feat, W, bias, h);
    }
}

// ===========================================================================
// Aggregate: TWO rows per wave (8 interleaved fma/gather chains for MLP),
// lane = channel.  pack gives 2-deep chain: pack[j] -> h[col].
// Fused epilogue: + skip_weight, SeLU.
// ===========================================================================
__global__ __launch_bounds__(256) void aggregate_pack_kernel(
    const int*   __restrict__ row_start,
    const uint2* __restrict__ pack,
    const float* __restrict__ h,
    const float* __restrict__ skip,
    float*       __restrict__ out)
{
    int pair = blockIdx.x * 4 + (threadIdx.x >> 6);   // wave id = row pair
    int lane = threadIdx.x & 63;
    int r0 = pair * 2;
    if (r0 >= N_NODES) return;
    int r1 = r0 + 1;                                  // N_NODES even -> valid

    int s0 = row_start[r0], e0 = row_start[r0 + 1];
    int s1 = row_start[r1], e1 = row_start[r1 + 1];
    float skp = skip[lane];

    float a0 = 0.f, a1 = 0.f, a2 = 0.f, a3 = 0.f;   // row0 chains
    float b0 = 0.f, b1 = 0.f, b2 = 0.f, b3 = 0.f;   // row1 chains

    int j0 = s0, j1 = s1;
    while (j0 < e0 || j1 < e1) {
        int cnt0 = e0 - j0; cnt0 = cnt0 < 0 ? 0 : (cnt0 > 64 ? 64 : cnt0);
        int cnt1 = e1 - j1; cnt1 = cnt1 < 0 ? 0 : (cnt1 > 64 ? 64 : cnt1);
        uint2 p0 = make_uint2(0u, 0u), p1 = make_uint2(0u, 0u);
        if (lane < cnt0) p0 = pack[j0 + lane];        // coalesced 512B
        if (lane < cnt1) p1 = pack[j1 + lane];
        int pc = cnt0 > cnt1 ? cnt0 : cnt1;
        pc = (pc + 3) & ~3;
        for (int k = 0; k < pc; k += 4) {
            // v=0 padding (zero-init p) -> fma contributes 0 for dead slots
            int   c00 = __shfl((int)p0.x, k + 0, 64); float v00 = __shfl(__uint_as_float(p0.y), k + 0, 64);
            int   c10 = __shfl((int)p1.x, k + 0, 64); float v10 = __shfl(__uint_as_float(p1.y), k + 0, 64);
            int   c01 = __shfl((int)p0.x, k + 1, 64); float v01 = __shfl(__uint_as_float(p0.y), k + 1, 64);
            int   c11 = __shfl((int)p1.x, k + 1, 64); float v11 = __shfl(__uint_as_float(p1.y), k + 1, 64);
            int   c02 = __shfl((int)p0.x, k + 2, 64); float v02 = __shfl(__uint_as_float(p0.y), k + 2, 64);
            int   c12 = __shfl((int)p1.x, k + 2, 64); float v12 = __shfl(__uint_as_float(p1.y), k + 2, 64);
            int   c03 = __shfl((int)p0.x, k + 3, 64); float v03 = __shfl(__uint_as_float(p0.y), k + 3, 64);
            int   c13 = __shfl((int)p1.x, k + 3, 64); float v13 = __shfl(__uint_as_float(p1.y), k + 3, 64);
            a0 = fmaf(v00, h[c00 * N_CH + lane], a0);
            b0 = fmaf(v10, h[c10 * N_CH + lane], b0);
            a1 = fmaf(v01, h[c01 * N_CH + lane], a1);
            b1 = fmaf(v11, h[c11 * N_CH + lane], b1);
            a2 = fmaf(v02, h[c02 * N_CH + lane], a2);
            b2 = fmaf(v12, h[c12 * N_CH + lane], b2);
            a3 = fmaf(v03, h[c03 * N_CH + lane], a3);
            b3 = fmaf(v13, h[c13 * N_CH + lane], b3);
        }
        j0 += 64; j1 += 64;
    }
    float x0 = (a0 + a1) + (a2 + a3) + skp;
    float x1 = (b0 + b1) + (b2 + b3) + skp;
    float n0 = SELU_SCALE * SELU_ALPHA * expm1f(x0);
    float n1 = SELU_SCALE * SELU_ALPHA * expm1f(x1);
    out[r0 * N_CH + lane] = x0 > 0.f ? SELU_SCALE * x0 : n0;
    out[r1 * N_CH + lane] = x1 > 0.f ? SELU_SCALE * x1 : n1;
}

// ===========================================================================
// Fallback path 1 (ws >= perm-need): measured R2 perm-based path
// ===========================================================================
__global__ __launch_bounds__(256) void scatter_gemm_kernel(
    const int* __restrict__ rows, const int* __restrict__ rank,
    const int* __restrict__ row_start, int* __restrict__ perm,
    const float* __restrict__ feat, const float* __restrict__ W,
    const float* __restrict__ bias, float* __restrict__ h)
{
    if (blockIdx.x < NB_SCAT4) {
        int i = blockIdx.x * 256 + threadIdx.x;
        if (i < N_EDGES / 4) {
            const int4 r  = reinterpret_cast<const int4*>(rows)[i];
            const int4 rk = reinterpret_cast<const int4*>(rank)[i];
            int e0 = i * 4;
            perm[row_start[r.x] + rk.x] = e0 + 0;
            perm[row_start[r.y] + rk.y] = e0 + 1;
            perm[row_start[r.z] + rk.z] = e0 + 2;
            perm[row_start[r.w] + rk.w] = e0 + 3;
        }
    } else {
        gemm_body(blockIdx.x - NB_SCAT4, feat, W, bias, h);
    }
}

__global__ __launch_bounds__(256) void aggregate_kernel(
    const int*   __restrict__ row_start,
    const int*   __restrict__ perm,
    const int*   __restrict__ cols,
    const float* __restrict__ vals,
    const float* __restrict__ h,
    const float* __restrict__ skip,
    float*       __restrict__ out)
{
    int row  = blockIdx.x * 4 + (threadIdx.x >> 6);
    int lane = threadIdx.x & 63;
    if (row >= N_NODES) return;

    int s = row_start[row];
    int e = row_start[row + 1];

    float a0 = 0.f, a1 = 0.f, a2 = 0.f, a3 = 0.f;
    for (int j = s; j < e; j += 64) {
        int cnt = e - j;
        if (cnt > 64) cnt = 64;
        int   c = 0;
        float v = 0.f;
        if (lane < cnt) {
            int eid = perm[j + lane];
            c = cols[eid];
            v = vals[eid];
        }
        int pc = (cnt + 3) & ~3;
        for (int k = 0; k < pc; k += 4) {
            int   c0 = __shfl(c, k + 0, 64);
            float v0 = __shfl(v, k + 0, 64);
            int   c1 = __shfl(c, k + 1, 64);
            float v1 = __shfl(v, k + 1, 64);
            int   c2 = __shfl(c, k + 2, 64);
            float v2 = __shfl(v, k + 2, 64);
            int   c3 = __shfl(c, k + 3, 64);
            float v3 = __shfl(v, k + 3, 64);
            a0 = fmaf(v0, h[c0 * N_CH + lane], a0);
            a1 = fmaf(v1, h[c1 * N_CH + lane], a1);
            a2 = fmaf(v2, h[c2 * N_CH + lane], a2);
            a3 = fmaf(v3, h[c3 * N_CH + lane], a3);
        }
    }
    float x = (a0 + a1) + (a2 + a3) + skip[lane];
    float neg = SELU_SCALE * SELU_ALPHA * expm1f(x);
    out[row * N_CH + lane] = x > 0.f ? SELU_SCALE * x : neg;
}

// ===========================================================================
// Fallback path 2 (tiny ws): Round-0 atomic version
// ===========================================================================
__global__ __launch_bounds__(256) void gemm_only_kernel(
    const float* __restrict__ feat, const float* __restrict__ W,
    const float* __restrict__ bias, float* __restrict__ h)
{
    gemm_body(blockIdx.x, feat, W, bias, h);
}

__global__ __launch_bounds__(256) void init_out_kernel(
    float* __restrict__ out, const float* __restrict__ skip)
{
    int idx = blockIdx.x * 256 + threadIdx.x;
    if (idx < N_NODES * N_CH) out[idx] = skip[idx & (N_CH - 1)];
}

__global__ __launch_bounds__(256) void edge_kernel(
    const float* __restrict__ vals, const int* __restrict__ rows,
    const int* __restrict__ cols, const float* __restrict__ h,
    float* __restrict__ out)
{
    int e = blockIdx.x * 4 + (threadIdx.x >> 6);
    int lane = threadIdx.x & 63;
    if (e >= N_EDGES) return;
    int row = rows[e];
    int col = cols[e];
    float v = vals[e];
    atomicAdd(&out[row * N_CH + lane], v * h[col * N_CH + lane]);
}

__global__ __launch_bounds__(256) void selu_kernel(float* __restrict__ out)
{
    int idx = blockIdx.x * 256 + threadIdx.x;
    if (idx >= N_NODES * N_CH) return;
    float x = out[idx];
    float neg = SELU_SCALE * SELU_ALPHA * expm1f(x);
    out[idx] = x > 0.f ? SELU_SCALE * x : neg;
}

// ===========================================================================
static inline size_t align256(size_t x) { return (x + 255) & ~(size_t)255; }

extern "C" void kernel_launch(void* const* d_in, const int* in_sizes, int n_in,
                              void* d_out, int out_size, void* d_ws, size_t ws_size,
                              hipStream_t stream)
{
    const float* features = (const float*)d_in[0];
    const float* W        = (const float*)d_in[1];
    const float* bias     = (const float*)d_in[2];
    const float* skip     = (const float*)d_in[3];
    const float* adj_vals = (const float*)d_in[4];
    const int*   adj_rows = (const int*)d_in[5];
    const int*   adj_cols = (const int*)d_in[6];
    float* out = (float*)d_out;

    // ---- workspace carve-up ----
    char* ws = (char*)d_ws;
    size_t off = 0;
    float* h       = (float*)(ws + off);  off = align256(off + (size_t)N_NODES * N_CH * 4);
    int* row_start = (int*)(ws + off);    off = align256(off + (size_t)(N_NODES + 1) * 4);
    int* deg       = (int*)(ws + off);    off = align256(off + (size_t)N_NODES * 4);
    int* partials  = (int*)(ws + off);    off = align256(off + 128 * 4);
    int* rank      = (int*)(ws + off);    off = align256(off + (size_t)N_EDGES * 4);
    size_t need_perm = off + align256((size_t)N_EDGES * 4);       // perm path
    size_t need_pack = off + align256((size_t)N_EDGES * 8);       // pack path
    int*   perm = (int*)(ws + off);
    unsigned long long* pack64 = (unsigned long long*)(ws + off);
    uint2* pack = (uint2*)(ws + off);

    if (ws_size >= need_pack) {
        // ---- main path: packed CSR ----
        zero_deg_kernel<<<(N_NODES + 255) / 256, 256, 0, stream>>>(deg);
        degree_rank_kernel<<<NB_SCAT4, 256, 0, stream>>>(adj_rows, deg, rank);
        scan1_kernel<<<SCAN_NB, SCAN_TPB, 0, stream>>>(deg, row_start, partials);
        scan2_kernel<<<1, 128, 0, stream>>>(partials);
        scan3_kernel<<<SCAN_NB, SCAN_TPB, 0, stream>>>(row_start, partials);
        scatter_pack_gemm_kernel<<<NB_SCAT4 + NB_GEMM, 256, 0, stream>>>(
            adj_rows, rank, adj_cols, adj_vals, row_start, pack64,
            features, W, bias, h);
        aggregate_pack_kernel<<<(N_NODES / 2 + 3) / 4, 256, 0, stream>>>(
            row_start, pack, h, skip, out);
    } else if (ws_size >= need_perm) {
        // ---- measured R2 path ----
        zero_deg_kernel<<<(N_NODES + 255) / 256, 256, 0, stream>>>(deg);
        degree_rank_kernel<<<NB_SCAT4, 256, 0, stream>>>(adj_rows, deg, rank);
        scan1_kernel<<<SCAN_NB, SCAN_TPB, 0, stream>>>(deg, row_start, partials);
        scan2_kernel<<<1, 128, 0, stream>>>(partials);
        scan3_kernel<<<SCAN_NB, SCAN_TPB, 0, stream>>>(row_start, partials);
        scatter_gemm_kernel<<<NB_SCAT4 + NB_GEMM, 256, 0, stream>>>(
            adj_rows, rank, row_start, perm, features, W, bias, h);
        aggregate_kernel<<<(N_NODES + 3) / 4, 256, 0, stream>>>(
            row_start, perm, adj_cols, adj_vals, h, skip, out);
    } else {
        // ---- fallback: atomic scatter ----
        gemm_only_kernel<<<NB_GEMM, 256, 0, stream>>>(features, W, bias, h);
        init_out_kernel<<<(N_NODES * N_CH + 255) / 256, 256, 0, stream>>>(out, skip);
        edge_kernel<<<(N_EDGES + 3) / 4, 256, 0, stream>>>(
            adj_vals, adj_rows, adj_cols, h, out);
        selu_kernel<<<(N_NODES * N_CH + 255) / 256, 256, 0, stream>>>(out);
    }
}